// Round 1
// baseline (182.621 us; speedup 1.0000x reference)
//
#include <hip/hip_runtime.h>

// ST-GCN fused block for MI355X (gfx950).  FP32 I/O, bf16 at MFMA boundaries.
// 3 dispatches: kprep (tiny, 8 blocks: tables + statsbuf/counter zero)
//            -> kmain (window-sum fused from x; 4-l blocks, dual-T1; BN stats
//               via 128-way replicated atomics; LAST block finalizes mean/var
//               into sc_sh via atomic-counter pattern)
//            -> kapply (pure streaming: BN+ReLU+residual, f32x4).
// zb layout: [n][l][w][c] bf16.  statsbuf: 128 copies x 128 f32.

typedef unsigned short ushort_t;
typedef __attribute__((ext_vector_type(8))) short short8;   // 8 x bf16 MFMA frag
typedef __attribute__((ext_vector_type(4))) float f32x4;
typedef __attribute__((ext_vector_type(4))) unsigned short us4;
typedef __attribute__((ext_vector_type(8))) unsigned short us8;

#define N_  4
#define CI_ 64
#define CO_ 64
#define L_  1024
#define V_  25
#define P_  3
#define KS_ 9
#define NLV 102400.0f   // N_*L_*V_  (BN population count per channel)
#define NREP 128        // stats replication factor
#define NBLK 1024       // kmain grid = 256 x N_

__device__ __forceinline__ float b2f(ushort_t u) {
  union { float f; unsigned int i; } c; c.i = ((unsigned int)u) << 16; return c.f;
}
__device__ __forceinline__ ushort_t f2b(float f) {
  union { float f; unsigned int i; } c; c.f = f;
  unsigned int u = c.i;
  u += 0x7fffu + ((u >> 16) & 1u);      // round-to-nearest-even
  return (ushort_t)(u >> 16);
}

// ---------------------------------------------------------------------------
// kprep: 8 small blocks build the constant tables and zero statsbuf+counter.
// b0: colA+biastab+counter, b1: a2, b2-3: wb, b4-7: statsbuf zero.
__global__ __launch_bounds__(256) void kprep(
    const float* __restrict__ A, const float* __restrict__ E,
    const float* __restrict__ W, const float* __restrict__ cb,
    ushort_t* __restrict__ a2, float* __restrict__ biastab,
    ushort_t* __restrict__ wb, float* __restrict__ statsbuf,
    unsigned int* __restrict__ counter)
{
  const int b = blockIdx.x, tid = threadIdx.x;
  if (b == 0) {
    __shared__ float colA[P_ * 32];
    if (tid < P_ * 32) {
      int p = tid >> 5, w = tid & 31;
      float s = 0.f;
      if (w < V_)
        for (int v = 0; v < V_; ++v) {
          int idx = (p * V_ + v) * V_ + w;
          s += A[idx] * E[idx];
        }
      colA[tid] = s;
    }
    if (tid == 0) *counter = 0u;
    __syncthreads();
    for (int e = tid; e < 32 * 64; e += 256) {
      int w = e >> 6, c = e & 63;
      float s = 0.f;
      for (int p = 0; p < P_; ++p) s += cb[p * 64 + c] * colA[p * 32 + w];
      biastab[e] = s;
    }
  } else if (b == 1) {
    for (int e = tid; e < 32 * 96; e += 256) {
      int w = e / 96, k = e - w * 96;
      int p = k >> 5, v = k & 31;
      float val = 0.f;
      if (w < V_ && v < V_) {
        int idx = (p * V_ + v) * V_ + w;
        val = A[idx] * E[idx];
      }
      a2[e] = f2b(val);
    }
  } else if (b < 4) {
    const int base = (b - 2) * 6144;
    for (int e = tid; e < 6144; e += 256) wb[base + e] = f2b(W[base + e]);
  } else {
    f32x4* sb = (f32x4*)statsbuf + (b - 4) * 1024;   // 4 blocks x 4096 f32
    for (int e = tid; e < 1024; e += 256) sb[e] = (f32x4){0.f, 0.f, 0.f, 0.f};
  }
}

// ---------------------------------------------------------------------------
// kmain: per-(n, 4 l's) block.
//   phase0: x slab (12 l's, fp32) -> bf16 tile (aliases T1) -> causal 9-window
//           sliding sums -> XT[l_][v][72ci]   (kwin fused in)
//   stage1 (2 passes, dual T1): t1 = Wb[192x64] @ Xs[64 x 64cols] per l-pair
//   stage2: z[c=64][w=32] per l = T1c[64x96] @ A2[96x32]; + cnt(l)*bias
//   epilogue: us4 zb stores + BN stats atomics; last block finalizes sc_sh.
__global__ __launch_bounds__(256) void kmain(
    const float*    __restrict__ x,       // [n][ci][l][v] f32
    const ushort_t* __restrict__ Wb,      // [192][64] bf16 (L1-hot)
    const ushort_t* __restrict__ a2,      // [32 w][96 k] bf16 (L1-hot)
    const float*    __restrict__ biastab, // [32 w][64 c] f32 (L1-hot)
    ushort_t*       __restrict__ zb,
    float*          __restrict__ statsbuf,
    unsigned int*   __restrict__ counter,
    const float*    __restrict__ gamma,
    const float*    __restrict__ beta,
    float*          __restrict__ sc_sh)
{
  const int lb = blockIdx.x;            // 4 l's per block (0..255)
  const int n  = blockIdx.y;
  const int tid = threadIdx.x, lane = tid & 63, wv = tid >> 6;
  const int m16 = lane & 15, quad = lane >> 4;

  __shared__ __align__(16) ushort_t XT[4 * 2304];    // [l_][v][72ci]  18.4 KB
  __shared__ __align__(16) ushort_t T1[2 * 13312];   // [pair][l_][c][104]  53.2 KB
  // phase0 bf16 x-tile [64 ci][302] (19,328 us) aliases T1 (consumed before
  // stage1's first T1 write; barriers separate the lifetimes).

  // ---- phase0a: load x slab l0-8..l0+3 (12 l x 25 v per ci), fp32->bf16 ----
  {
    ushort_t* tile = T1;
    const float* xb = x + (long)n * (CI_ * L_ * V_) + (long)(4 * lb - 8) * V_;
    const int zlim = 200 - 100 * lb;    // # leading f32 in l<0 halo (lb 0/1)
    for (int m = tid; m < 4800; m += 256) {        // 64 ci x 75 f32x4
      int ci = m / 75, j4 = (m - ci * 75) * 4;     // j4 = 0..296
      f32x4 d;
      if (j4 < zlim) d = (f32x4){0.f, 0.f, 0.f, 0.f};
      else d = *(const f32x4*)(xb + (long)ci * (L_ * V_) + j4);
      unsigned int p0 = ((unsigned int)f2b(d[1]) << 16) | f2b(d[0]);
      unsigned int p1 = ((unsigned int)f2b(d[3]) << 16) | f2b(d[2]);
      *(unsigned int*)(&tile[ci * 302 + j4])     = p0;
      *(unsigned int*)(&tile[ci * 302 + j4 + 2]) = p1;
    }
  }
  __syncthreads();

  // ---- phase0b: sliding causal window -> XT; zero-pad v rows 25..31 ----
  {
    const ushort_t* tile = T1;
    for (int cid = tid; cid < 1600; cid += 256) {
      const int v = cid >> 6, ci = cid & 63;
      const ushort_t* col = &tile[ci * 302 + v];   // stride 25 along l
      float s = 0.f;
#pragma unroll
      for (int li = 0; li < 9; ++li) s += b2f(col[li * 25]);
      XT[v * 72 + ci] = f2b(s);                    // l_ = 0
#pragma unroll
      for (int l_ = 1; l_ < 4; ++l_) {
        s += b2f(col[(l_ + 8) * 25]) - b2f(col[(l_ - 1) * 25]);
        XT[l_ * 2304 + v * 72 + ci] = f2b(s);
      }
    }
    if (tid < 252) {                    // 4 l_ x 63 us8 = pad rows 25..31
      int l_ = tid / 63, j = tid - l_ * 63;
      *(us8*)(&XT[l_ * 2304 + 1800 + j * 8]) = (us8){0,0,0,0,0,0,0,0};
    }
  }
  __syncthreads();

  // hoist Wb A-frags once (reused by both stage-1 passes)
  short8 af[3][2];
#pragma unroll
  for (int i = 0; i < 3; ++i) {
    const ushort_t* wrow = Wb + ((wv * 3 + i) * 16 + m16) * 64 + quad * 8;
    af[i][0] = *(const short8*)(wrow);
    af[i][1] = *(const short8*)(wrow + 32);
  }

  // ---- stage 1: two passes (l01 -> T1[0], l23 -> T1[1]); 24 MFMA each ----
#pragma unroll
  for (int pair = 0; pair < 2; ++pair) {
    short8 bfr[4][2];
#pragma unroll
    for (int nt = 0; nt < 4; ++nt)
#pragma unroll
      for (int ks = 0; ks < 2; ++ks)
        bfr[nt][ks] = *(const short8*)(
            &XT[(pair * 2 + (nt >> 1)) * 2304 + ((nt & 1) * 16 + m16) * 72 + ks * 32 + quad * 8]);

    f32x4 acc1[3][4];
#pragma unroll
    for (int i = 0; i < 3; ++i)
#pragma unroll
      for (int j = 0; j < 4; ++j) acc1[i][j] = (f32x4){0.f, 0.f, 0.f, 0.f};

#pragma unroll
    for (int i = 0; i < 3; ++i)
#pragma unroll
      for (int nt = 0; nt < 4; ++nt) {
        acc1[i][nt] = __builtin_amdgcn_mfma_f32_16x16x32_bf16(af[i][0], bfr[nt][0], acc1[i][nt], 0, 0, 0);
        acc1[i][nt] = __builtin_amdgcn_mfma_f32_16x16x32_bf16(af[i][1], bfr[nt][1], acc1[i][nt], 0, 0, 0);
      }
    // repack t1 -> T1[pair][l_][c][p*32+v]  (D: row = quad*4+r, col = m16)
#pragma unroll
    for (int i = 0; i < 3; ++i) {
      const int mt = wv * 3 + i;
#pragma unroll
      for (int nt = 0; nt < 4; ++nt) {
        const int l_ = nt >> 1;
        const int col = (nt & 1) * 16 + m16;
#pragma unroll
        for (int r = 0; r < 4; ++r) {
          int k = mt * 16 + quad * 4 + r;        // k = p*64 + c
          T1[pair * 13312 + l_ * 6656 + (k & 63) * 104 + (k >> 6) * 32 + col] = f2b(acc1[i][nt][r]);
        }
      }
    }
  }
  __syncthreads();

  // ---- stage 2: 12 MFMA per pair; a2 B-frags loaded once (global, L1-hot) ----
  short8 bfr2[2][3];
#pragma unroll
  for (int nt = 0; nt < 2; ++nt)
#pragma unroll
    for (int ks = 0; ks < 3; ++ks)
      bfr2[nt][ks] = *(const short8*)(a2 + (nt * 16 + m16) * 96 + ks * 32 + quad * 8);

  const int cbase = wv * 16 + quad * 4;
  float s1[4] = {0.f, 0.f, 0.f, 0.f}, s2[4] = {0.f, 0.f, 0.f, 0.f};
#pragma unroll
  for (int pair = 0; pair < 2; ++pair) {
    f32x4 acc2[2][2];
#pragma unroll
    for (int l_ = 0; l_ < 2; ++l_)
#pragma unroll
      for (int nt = 0; nt < 2; ++nt) acc2[l_][nt] = (f32x4){0.f, 0.f, 0.f, 0.f};

#pragma unroll
    for (int l_ = 0; l_ < 2; ++l_)
#pragma unroll
      for (int ks = 0; ks < 3; ++ks) {
        short8 afT = *(const short8*)(&T1[pair * 13312 + l_ * 6656 + (wv * 16 + m16) * 104 + ks * 32 + quad * 8]);
        acc2[l_][0] = __builtin_amdgcn_mfma_f32_16x16x32_bf16(afT, bfr2[0][ks], acc2[l_][0], 0, 0, 0);
        acc2[l_][1] = __builtin_amdgcn_mfma_f32_16x16x32_bf16(afT, bfr2[1][ks], acc2[l_][1], 0, 0, 0);
      }

    // epilogue: + cnt(l)*bias (float4), us4 store; accumulate BN stats
#pragma unroll
    for (int l_ = 0; l_ < 2; ++l_) {
      const int l = 4 * lb + pair * 2 + l_;
      const float cnt = (float)(l + 1 < KS_ ? l + 1 : KS_);
#pragma unroll
      for (int nt = 0; nt < 2; ++nt) {
        const int w = nt * 16 + m16;
        if (w < V_) {
          f32x4 bias = *(const f32x4*)(biastab + w * 64 + cbase);
          us4 pack;
#pragma unroll
          for (int r = 0; r < 4; ++r) {
            pack[r] = f2b(acc2[l_][nt][r] + cnt * bias[r]);
            float zr = b2f(pack[r]);            // stats on the stored value
            s1[r] += zr; s2[r] += zr * zr;
          }
          *(us4*)(&zb[(((long)(n * L_ + l) * V_ + w) << 6) + cbase]) = pack;
        }
      }
    }
  }
  // in-quad reduction over m16 (lanes of a quad share channels cbase..cbase+3)
#pragma unroll
  for (int off = 1; off < 16; off <<= 1) {
#pragma unroll
    for (int r = 0; r < 4; ++r) {
      s1[r] += __shfl_xor(s1[r], off, 64);
      s2[r] += __shfl_xor(s2[r], off, 64);
    }
  }
  if (m16 == 0) {
    float* sb = statsbuf + ((n * 256 + lb) & (NREP - 1)) * 128;
#pragma unroll
    for (int r = 0; r < 4; ++r) {
      atomicAdd(&sb[cbase + r], s1[r]);
      atomicAdd(&sb[64 + cbase + r], s2[r]);
    }
  }

  // ---- last-block finalize: reduce NREP copies -> sc/sh table ----
  __syncthreads();                      // all waves' atomics drained (vmcnt 0)
  __shared__ int lastFlag;
  if (tid == 0) {
    __threadfence();
    lastFlag = (atomicAdd(counter, 1u) == (unsigned int)(NBLK - 1)) ? 1 : 0;
  }
  __syncthreads();
  if (!lastFlag) return;

  __threadfence();
  __shared__ float part[256];
  {
    const int slot = tid & 127, half = tid >> 7;
    float a = 0.f;
    for (int k = half; k < NREP; k += 2)
      a += __hip_atomic_load(&statsbuf[k * 128 + slot],
                             __ATOMIC_RELAXED, __HIP_MEMORY_SCOPE_AGENT);
    part[tid] = a;
  }
  __syncthreads();
  if (tid < 64) {
    const float inv = 1.0f / NLV;
    float s    = part[tid]      + part[128 + tid];
    float sq   = part[64 + tid] + part[192 + tid];
    float mean = s * inv;
    float var  = sq * inv - mean * mean;
    float rstd = rsqrtf(var + 1e-5f);
    float g = gamma[tid];
    sc_sh[tid]      = rstd * g;
    sc_sh[64 + tid] = beta[tid] - mean * rstd * g;
  }
}

// ---------------------------------------------------------------------------
// kapply: pure streaming. out[n,c,l,v] = relu(relu((z)*sc[c]+sh[c]) + x).
// 4 l's per block; f32x4 on the (l,v)-contiguous axis.
__global__ __launch_bounds__(256) void kapply(
    const ushort_t* __restrict__ zb, const float* __restrict__ x,
    const float* __restrict__ sc_sh, float* __restrict__ out)
{
  const int n = blockIdx.y, chunk = blockIdx.x;   // 4 l's per block
  const int tid = threadIdx.x;
  __shared__ ushort_t zl[100 * 66];               // 13.2 KB transpose staging
  __shared__ float sc[64], sh[64];
  const long zbase = (long)((n * L_ + chunk * 4) * V_) * 64;   // 6400 elems
  for (int m = tid; m < 3200; m += 256) {         // u32 = 2 bf16
    *(unsigned int*)(&zl[(m >> 5) * 66 + (m & 31) * 2]) =
        ((const unsigned int*)(zb + zbase))[m];
  }
  if (tid < 64) { sc[tid] = sc_sh[tid]; sh[tid] = sc_sh[64 + tid]; }
  __syncthreads();
  const long obase = ((long)(n * 64) * L_ + chunk * 4) * V_;   // + c*25600 + rr
  for (int m = tid; m < 1600; m += 256) {
    int c = m / 25, q = m - c * 25, rr = q * 4;   // rr = 4-aligned l*25+v
    long xi = obase + (long)c * (L_ * V_) + rr;
    f32x4 xv = *(const f32x4*)(x + xi);
    f32x4 o;
#pragma unroll
    for (int j = 0; j < 4; ++j) {
      float z = b2f(zl[(rr + j) * 66 + c]);
      float y = fmaxf(z * sc[c] + sh[c], 0.f);
      o[j] = fmaxf(y + xv[j], 0.f);
    }
    *(f32x4*)(out + xi) = o;
  }
}

// ---------------------------------------------------------------------------
extern "C" void kernel_launch(void* const* d_in, const int* in_sizes, int n_in,
                              void* d_out, int out_size, void* d_ws, size_t ws_size,
                              hipStream_t stream)
{
  const float* x     = (const float*)d_in[0];
  const float* A     = (const float*)d_in[1];
  const float* E     = (const float*)d_in[2];
  const float* W     = (const float*)d_in[3];
  const float* cb    = (const float*)d_in[4];
  const float* gamma = (const float*)d_in[5];
  const float* beta  = (const float*)d_in[6];
  float* out = (float*)d_out;

  char* ws = (char*)d_ws;
  const size_t ZB_OFF   = 0;                       // 13,107,200 B (bf16 zb)
  const size_t WB_OFF   = 13107200;                // 24,576 B (bf16 Wb)
  const size_t A2_OFF   = WB_OFF + 32768;          // 6,144 B
  const size_t BIAS_OFF = A2_OFF + 16384;          // 8,192 B
  const size_t STAT_OFF = BIAS_OFF + 16384;        // 65,536 B (128 x 128 f32)
  const size_t CNT_OFF  = STAT_OFF + 65536;        // 4 B counter
  const size_t SCSH_OFF = CNT_OFF + 256;           // 512 B sc/sh table
  ushort_t* zb       = (ushort_t*)(ws + ZB_OFF);
  ushort_t* wb       = (ushort_t*)(ws + WB_OFF);
  ushort_t* a2       = (ushort_t*)(ws + A2_OFF);
  float*    biastab  = (float*)(ws + BIAS_OFF);
  float*    statsbuf = (float*)(ws + STAT_OFF);
  unsigned int* counter = (unsigned int*)(ws + CNT_OFF);
  float*    sc_sh    = (float*)(ws + SCSH_OFF);

  kprep <<<dim3(8), 256, 0, stream>>>(A, E, W, cb, a2, biastab, wb, statsbuf, counter);
  kmain <<<dim3(256, N_), 256, 0, stream>>>(x, wb, a2, biastab, zb, statsbuf,
                                            counter, gamma, beta, sc_sh);
  kapply<<<dim3(256, N_), 256, 0, stream>>>(zb, x, sc_sh, out);
}

// Round 2
// 173.930 us; speedup vs baseline: 1.0500x; 1.0500x over previous
//
#include <hip/hip_runtime.h>

// ST-GCN fused block for MI355X (gfx950).  FP32 I/O, bf16 at MFMA boundaries.
// 3 dispatches: kwin(+prep: tables, statsbuf/counter zero)
//            -> kmain (4-l blocks, dual-T1, 2 barriers; BN-stats via 128-way
//               replicated atomics; LAST block finalizes mean/var -> sc_sh)
//            -> kapply (pure streaming: BN+ReLU+residual, f32x4, 8-l blocks).
// xs layout: [n][l][25 v][64 ci] bf16.   zb layout: [n][l][w][c] bf16.
// statsbuf: 128 copies x 128 f32 -> 8 atomics/address.

typedef unsigned short ushort_t;
typedef __attribute__((ext_vector_type(8))) short short8;   // 8 x bf16 MFMA frag
typedef __attribute__((ext_vector_type(4))) float f32x4;
typedef __attribute__((ext_vector_type(4))) unsigned short us4;
typedef __attribute__((ext_vector_type(8))) unsigned short us8;

#define N_  4
#define CI_ 64
#define CO_ 64
#define L_  1024
#define V_  25
#define P_  3
#define KS_ 9
#define NLV 102400.0f   // N_*L_*V_  (BN population count per channel)
#define NREP 128        // stats replication factor
#define NBLK 1024       // kmain grid = 256 x N_

__device__ __forceinline__ float b2f(ushort_t u) {
  union { float f; unsigned int i; } c; c.i = ((unsigned int)u) << 16; return c.f;
}
__device__ __forceinline__ ushort_t f2b(float f) {
  union { float f; unsigned int i; } c; c.f = f;
  unsigned int u = c.i;
  u += 0x7fffu + ((u >> 16) & 1u);      // round-to-nearest-even
  return (ushort_t)(u >> 16);
}

// ---------------------------------------------------------------------------
// kwin: causal 9-wide window-sum along l, fp32 x -> bf16 xs[n][l][25*64].
// block = (chunk of 8 l's, n); chunk==128 & n==0 does prep instead.
__global__ __launch_bounds__(256) void kwin(
    const float* __restrict__ x, ushort_t* __restrict__ xs,
    const float* __restrict__ A, const float* __restrict__ E,
    const float* __restrict__ cb, const float* __restrict__ W,
    ushort_t* __restrict__ a2raw, float* __restrict__ biastab,
    ushort_t* __restrict__ wb, float* __restrict__ statsbuf,
    unsigned int* __restrict__ counter)
{
  const int chunk = blockIdx.x;                 // 0..128
  const int n = blockIdx.y;
  const int tid = threadIdx.x;

  if (chunk == 128) {                           // ---- prep block ----
    if (n != 0) return;
    __shared__ float colA[P_ * 32];
    if (tid < P_ * 32) {
      int p = tid >> 5, w = tid & 31;
      float s = 0.f;
      if (w < V_)
        for (int v = 0; v < V_; ++v) {
          int idx = (p * V_ + v) * V_ + w;
          s += A[idx] * E[idx];
        }
      colA[tid] = s;
    }
    if (tid == 0) *counter = 0u;
    for (int e = tid; e < 32 * 96; e += 256) {
      int w = e / 96, k = e - w * 96;
      int p = k >> 5, v = k & 31;
      float val = 0.f;
      if (w < V_ && v < V_) {
        int idx = (p * V_ + v) * V_ + w;
        val = A[idx] * E[idx];
      }
      a2raw[e] = f2b(val);
    }
    for (int e = tid; e < 192 * 64; e += 256) wb[e] = f2b(W[e]);
    __syncthreads();
    for (int e = tid; e < 32 * 64; e += 256) {
      int w = e >> 6, c = e & 63;
      float s = 0.f;
      for (int p = 0; p < P_; ++p) s += cb[p * 64 + c] * colA[p * 32 + w];
      biastab[e] = s;
    }
    for (int e = tid; e < NREP * 128; e += 256) statsbuf[e] = 0.f;
    return;
  }

  // ---- window block ----
  __shared__ ushort_t tile[64 * 402];           // 51.5 KB; stride 402 (odd dword)
  const int l0 = chunk * 8;
  const long xn = (long)n * CI_ * L_ * V_;
  for (int m = tid; m < 6400; m += 256) {       // 64 ci x 400 f32 -> bf16
    int ci = m / 100;
    int j4 = (m - ci * 100) * 4;                // 0..396
    f32x4 d;
    if (chunk == 0 && j4 < 200) {
      d = (f32x4){0.f, 0.f, 0.f, 0.f};          // l < 0 halo (li 0..7)
    } else {
      d = *(const f32x4*)(x + xn + (long)ci * (L_ * V_) + (l0 - 8) * V_ + j4);
    }
    ushort_t* dst = &tile[ci * 402 + j4];
    dst[0] = f2b(d[0]); dst[1] = f2b(d[1]); dst[2] = f2b(d[2]); dst[3] = f2b(d[3]);
  }
  __syncthreads();
  // sliding window per (v,ci) column; coalesced b16 stores per l_.
  const long xsbase = ((long)n * L_ + l0) * 1600;
  for (int cid = tid; cid < 1600; cid += 256) {
    const int v = cid >> 6, ci = cid & 63;
    const ushort_t* col = &tile[ci * 402 + v];  // + li*25 steps along l
    float s = 0.f;
#pragma unroll
    for (int li = 0; li < 9; ++li) s += b2f(col[li * 25]);
    xs[xsbase + cid] = f2b(s);                  // l_ = 0 (li window 0..8)
#pragma unroll
    for (int l_ = 1; l_ < 8; ++l_) {
      s += b2f(col[(l_ + 8) * 25]) - b2f(col[(l_ - 1) * 25]);
      xs[xsbase + l_ * 1600 + cid] = f2b(s);
    }
  }
}

// ---------------------------------------------------------------------------
// kmain: per-(n, 4 l's) block, 2 barriers in the hot path.
//   stage1 (2 passes, dual T1): t1 = Wb[192x64] @ Xs[64 x 64cols] per l-pair
//   stage2: z[c=64][w=32] per l = T1c[64x96] @ A2[96x32]; + cnt(l)*bias
//   epilogue: us4 zb stores + BN stats atomics; last block finalizes sc_sh.
__global__ __launch_bounds__(256) void kmain(
    const ushort_t* __restrict__ xs,      // [n][l][1600] bf16
    const ushort_t* __restrict__ Wb,      // [192][64] bf16 (L1-hot)
    const ushort_t* __restrict__ a2,      // [32 w][96 k] bf16 (L1-hot)
    const float*    __restrict__ biastab, // [32 w][64 c] f32 (L1-hot)
    ushort_t*       __restrict__ zb,
    float*          __restrict__ statsbuf,
    unsigned int*   __restrict__ counter,
    const float*    __restrict__ gamma,
    const float*    __restrict__ beta,
    float*          __restrict__ sc_sh)
{
  const int lb = blockIdx.x;            // 4 l's per block (0..255)
  const int n  = blockIdx.y;
  const int tid = threadIdx.x, lane = tid & 63, wv = tid >> 6;
  const int m16 = lane & 15, quad = lane >> 4;

  __shared__ __align__(16) ushort_t XT[4 * 2304];    // [l_][v][72ci]  18.4 KB
  __shared__ __align__(16) ushort_t T1[2 * 13312];   // [pair][l_][c][104]  53.2 KB

  // stage XT: 6400 contiguous bf16 -> 800 us8 chunks; zero pad rows v=25..31
  {
    const ushort_t* src = xs + ((long)n * L_ + 4 * lb) * 1600;
    for (int m = tid; m < 800; m += 256) {
      int l_ = m / 200, mr = m - l_ * 200;
      int v = mr >> 3, sub = mr & 7;
      *(us8*)(&XT[l_ * 2304 + v * 72 + sub * 8]) = *(const us8*)(src + m * 8);
    }
    if (tid < 252) {                    // 4 l_ x 63 us8 = pad rows 25..31
      int l_ = tid / 63, j = tid - l_ * 63;
      *(us8*)(&XT[l_ * 2304 + 1800 + j * 8]) = (us8){0,0,0,0,0,0,0,0};
    }
  }
  __syncthreads();

  // hoist Wb A-frags once (reused by both stage-1 passes)
  short8 af[3][2];
#pragma unroll
  for (int i = 0; i < 3; ++i) {
    const ushort_t* wrow = Wb + ((wv * 3 + i) * 16 + m16) * 64 + quad * 8;
    af[i][0] = *(const short8*)(wrow);
    af[i][1] = *(const short8*)(wrow + 32);
  }

  // ---- stage 1: two passes (l01 -> T1[0], l23 -> T1[1]); 24 MFMA each ----
#pragma unroll
  for (int pair = 0; pair < 2; ++pair) {
    short8 bfr[4][2];
#pragma unroll
    for (int nt = 0; nt < 4; ++nt)
#pragma unroll
      for (int ks = 0; ks < 2; ++ks)
        bfr[nt][ks] = *(const short8*)(
            &XT[(pair * 2 + (nt >> 1)) * 2304 + ((nt & 1) * 16 + m16) * 72 + ks * 32 + quad * 8]);

    f32x4 acc1[3][4];
#pragma unroll
    for (int i = 0; i < 3; ++i)
#pragma unroll
      for (int j = 0; j < 4; ++j) acc1[i][j] = (f32x4){0.f, 0.f, 0.f, 0.f};

#pragma unroll
    for (int i = 0; i < 3; ++i)
#pragma unroll
      for (int nt = 0; nt < 4; ++nt) {
        acc1[i][nt] = __builtin_amdgcn_mfma_f32_16x16x32_bf16(af[i][0], bfr[nt][0], acc1[i][nt], 0, 0, 0);
        acc1[i][nt] = __builtin_amdgcn_mfma_f32_16x16x32_bf16(af[i][1], bfr[nt][1], acc1[i][nt], 0, 0, 0);
      }
    // repack t1 -> T1[pair][l_][c][p*32+v]  (D: row = quad*4+r, col = m16)
#pragma unroll
    for (int i = 0; i < 3; ++i) {
      const int mt = wv * 3 + i;
#pragma unroll
      for (int nt = 0; nt < 4; ++nt) {
        const int l_ = nt >> 1;
        const int col = (nt & 1) * 16 + m16;
#pragma unroll
        for (int r = 0; r < 4; ++r) {
          int k = mt * 16 + quad * 4 + r;        // k = p*64 + c
          T1[pair * 13312 + l_ * 6656 + (k & 63) * 104 + (k >> 6) * 32 + col] = f2b(acc1[i][nt][r]);
        }
      }
    }
  }
  __syncthreads();

  // ---- stage 2: 12 MFMA per pair; a2 B-frags loaded once (global, L1-hot) ----
  short8 bfr2[2][3];
#pragma unroll
  for (int nt = 0; nt < 2; ++nt)
#pragma unroll
    for (int ks = 0; ks < 3; ++ks)
      bfr2[nt][ks] = *(const short8*)(a2 + (nt * 16 + m16) * 96 + ks * 32 + quad * 8);

  const int cbase = wv * 16 + quad * 4;
  float s1[4] = {0.f, 0.f, 0.f, 0.f}, s2[4] = {0.f, 0.f, 0.f, 0.f};
#pragma unroll
  for (int pair = 0; pair < 2; ++pair) {
    f32x4 acc2[2][2];
#pragma unroll
    for (int l_ = 0; l_ < 2; ++l_)
#pragma unroll
      for (int nt = 0; nt < 2; ++nt) acc2[l_][nt] = (f32x4){0.f, 0.f, 0.f, 0.f};

#pragma unroll
    for (int l_ = 0; l_ < 2; ++l_)
#pragma unroll
      for (int ks = 0; ks < 3; ++ks) {
        short8 afT = *(const short8*)(&T1[pair * 13312 + l_ * 6656 + (wv * 16 + m16) * 104 + ks * 32 + quad * 8]);
        acc2[l_][0] = __builtin_amdgcn_mfma_f32_16x16x32_bf16(afT, bfr2[0][ks], acc2[l_][0], 0, 0, 0);
        acc2[l_][1] = __builtin_amdgcn_mfma_f32_16x16x32_bf16(afT, bfr2[1][ks], acc2[l_][1], 0, 0, 0);
      }

    // epilogue: + cnt(l)*bias (float4), us4 store; accumulate BN stats
#pragma unroll
    for (int l_ = 0; l_ < 2; ++l_) {
      const int l = 4 * lb + pair * 2 + l_;
      const float cnt = (float)(l + 1 < KS_ ? l + 1 : KS_);
#pragma unroll
      for (int nt = 0; nt < 2; ++nt) {
        const int w = nt * 16 + m16;
        if (w < V_) {
          f32x4 bias = *(const f32x4*)(biastab + w * 64 + cbase);
          us4 pack;
#pragma unroll
          for (int r = 0; r < 4; ++r) {
            pack[r] = f2b(acc2[l_][nt][r] + cnt * bias[r]);
            float zr = b2f(pack[r]);            // stats on the stored value
            s1[r] += zr; s2[r] += zr * zr;
          }
          *(us4*)(&zb[(((long)(n * L_ + l) * V_ + w) << 6) + cbase]) = pack;
        }
      }
    }
  }
  // in-quad reduction over m16 (lanes of a quad share channels cbase..cbase+3)
#pragma unroll
  for (int off = 1; off < 16; off <<= 1) {
#pragma unroll
    for (int r = 0; r < 4; ++r) {
      s1[r] += __shfl_xor(s1[r], off, 64);
      s2[r] += __shfl_xor(s2[r], off, 64);
    }
  }
  if (m16 == 0) {
    float* sb = statsbuf + ((n * 256 + lb) & (NREP - 1)) * 128;
#pragma unroll
    for (int r = 0; r < 4; ++r) {
      atomicAdd(&sb[cbase + r], s1[r]);
      atomicAdd(&sb[64 + cbase + r], s2[r]);
    }
  }

  // ---- last-block finalize: reduce NREP copies -> sc/sh table ----
  __syncthreads();
  __shared__ int lastFlag;
  if (tid == 0) {
    __threadfence();
    lastFlag = (atomicAdd(counter, 1u) == (unsigned int)(NBLK - 1)) ? 1 : 0;
  }
  __syncthreads();
  if (!lastFlag) return;

  __threadfence();
  __shared__ float part[256];
  {
    const int slot = tid & 127, half = tid >> 7;
    float a = 0.f;
    for (int k = half; k < NREP; k += 2)
      a += __hip_atomic_load(&statsbuf[k * 128 + slot],
                             __ATOMIC_RELAXED, __HIP_MEMORY_SCOPE_AGENT);
    part[tid] = a;
  }
  __syncthreads();
  if (tid < 64) {
    const float inv = 1.0f / NLV;
    float s    = part[tid]      + part[128 + tid];
    float sq   = part[64 + tid] + part[192 + tid];
    float mean = s * inv;
    float var  = sq * inv - mean * mean;
    float rstd = rsqrtf(var + 1e-5f);
    float g = gamma[tid];
    sc_sh[tid]      = rstd * g;
    sc_sh[64 + tid] = beta[tid] - mean * rstd * g;
  }
}

// ---------------------------------------------------------------------------
// kapply: pure streaming. out[n,c,l,v] = relu(relu(z*sc[c]+sh[c]) + x).
// 8 l's per block; f32x4 on the (l,v)-contiguous axis.
__global__ __launch_bounds__(256) void kapply(
    const ushort_t* __restrict__ zb, const float* __restrict__ x,
    const float* __restrict__ sc_sh, float* __restrict__ out)
{
  const int n = blockIdx.y, chunk = blockIdx.x;   // 8 l's per block
  const int tid = threadIdx.x;
  __shared__ ushort_t zl[200 * 66];               // 26.4 KB transpose staging
  __shared__ float sc[64], sh[64];
  const long zbase = (long)((n * L_ + chunk * 8) * V_) * 64;   // 12800 elems
  for (int m = tid; m < 6400; m += 256) {         // u32 = 2 bf16
    *(unsigned int*)(&zl[(m >> 5) * 66 + (m & 31) * 2]) =
        ((const unsigned int*)(zb + zbase))[m];
  }
  if (tid < 64) { sc[tid] = sc_sh[tid]; sh[tid] = sc_sh[64 + tid]; }
  __syncthreads();
  const long obase = ((long)(n * 64) * L_ + chunk * 8) * V_;   // + c*25600 + rr
  for (int m = tid; m < 3200; m += 256) {
    int c = m / 50, q = m - c * 50, rr = q * 4;   // rr = 4-aligned l*25+v
    long xi = obase + (long)c * (L_ * V_) + rr;
    f32x4 xv = *(const f32x4*)(x + xi);
    f32x4 o;
#pragma unroll
    for (int j = 0; j < 4; ++j) {
      float z = b2f(zl[(rr + j) * 66 + c]);
      float y = fmaxf(z * sc[c] + sh[c], 0.f);
      o[j] = fmaxf(y + xv[j], 0.f);
    }
    *(f32x4*)(out + xi) = o;
  }
}

// ---------------------------------------------------------------------------
extern "C" void kernel_launch(void* const* d_in, const int* in_sizes, int n_in,
                              void* d_out, int out_size, void* d_ws, size_t ws_size,
                              hipStream_t stream)
{
  const float* x     = (const float*)d_in[0];
  const float* A     = (const float*)d_in[1];
  const float* E     = (const float*)d_in[2];
  const float* W     = (const float*)d_in[3];
  const float* cb    = (const float*)d_in[4];
  const float* gamma = (const float*)d_in[5];
  const float* beta  = (const float*)d_in[6];
  float* out = (float*)d_out;

  char* ws = (char*)d_ws;
  const size_t XS_OFF   = 0;                       // 13,107,200 B (bf16 xs)
  const size_t ZB_OFF   = 13107200;                // 13,107,200 B (bf16 zb)
  const size_t WB_OFF   = 26214400;                // 24,576 B (bf16 Wb)
  const size_t A2_OFF   = WB_OFF + 32768;          // 6,144 B
  const size_t BIAS_OFF = A2_OFF + 16384;          // 8,192 B
  const size_t STAT_OFF = BIAS_OFF + 16384;        // 65,536 B (128 x 128 f32)
  const size_t CNT_OFF  = STAT_OFF + 65536;        // 4 B counter
  const size_t SCSH_OFF = CNT_OFF + 256;           // 512 B sc/sh table
  ushort_t* xs       = (ushort_t*)(ws + XS_OFF);
  ushort_t* zb       = (ushort_t*)(ws + ZB_OFF);
  ushort_t* wb       = (ushort_t*)(ws + WB_OFF);
  ushort_t* a2       = (ushort_t*)(ws + A2_OFF);
  float*    biastab  = (float*)(ws + BIAS_OFF);
  float*    statsbuf = (float*)(ws + STAT_OFF);
  unsigned int* counter = (unsigned int*)(ws + CNT_OFF);
  float*    sc_sh    = (float*)(ws + SCSH_OFF);

  kwin  <<<dim3(129, N_), 256, 0, stream>>>(x, xs, A, E, cb, W, a2, biastab, wb,
                                            statsbuf, counter);
  kmain <<<dim3(256, N_), 256, 0, stream>>>(xs, wb, a2, biastab, zb, statsbuf,
                                            counter, gamma, beta, sc_sh);
  kapply<<<dim3(128, N_), 256, 0, stream>>>(zb, x, sc_sh, out);
}

// Round 4
// 135.127 us; speedup vs baseline: 1.3515x; 1.2872x over previous
//
#include <hip/hip_runtime.h>

// ST-GCN fused block for MI355X (gfx950).  FP32 I/O, bf16 at MFMA boundaries.
// 3 dispatches: kwin(+prep: tables, statsbuf zero)
//            -> kmain (4-l blocks; stage-1 B-frags DIRECT from global xs
//               (L2-hot, v>=25 predicated-zero); single 26.6 KB T1, 3 barriers,
//               ~4 blocks/CU; BN-stats via 128-way replicated atomics)
//            -> kapply (statsbuf reduce (L2-hot) + BN+ReLU+residual, f32x4,
//               8-l blocks).
// xs layout: [n][l][25 v][64 ci] bf16.   zb layout: [n][l][w][c] bf16.
// statsbuf: 128 copies x 128 f32 -> 8 atomics/address.

typedef unsigned short ushort_t;
typedef __attribute__((ext_vector_type(8))) short short8;   // 8 x bf16 MFMA frag
typedef __attribute__((ext_vector_type(4))) float f32x4;
typedef __attribute__((ext_vector_type(4))) unsigned short us4;
typedef __attribute__((ext_vector_type(8))) unsigned short us8;

#define N_  4
#define CI_ 64
#define CO_ 64
#define L_  1024
#define V_  25
#define P_  3
#define KS_ 9
#define NLV 102400.0f   // N_*L_*V_  (BN population count per channel)
#define NREP 128        // stats replication factor

__device__ __forceinline__ float b2f(ushort_t u) {
  union { float f; unsigned int i; } c; c.i = ((unsigned int)u) << 16; return c.f;
}
__device__ __forceinline__ ushort_t f2b(float f) {
  union { float f; unsigned int i; } c; c.f = f;
  unsigned int u = c.i;
  u += 0x7fffu + ((u >> 16) & 1u);      // round-to-nearest-even
  return (ushort_t)(u >> 16);
}

// ---------------------------------------------------------------------------
// kwin: causal 9-wide window-sum along l, fp32 x -> bf16 xs[n][l][25*64].
// block = (chunk of 8 l's, n); chunk==128 & n==0 does prep instead.
__global__ __launch_bounds__(256) void kwin(
    const float* __restrict__ x, ushort_t* __restrict__ xs,
    const float* __restrict__ A, const float* __restrict__ E,
    const float* __restrict__ cb, const float* __restrict__ W,
    ushort_t* __restrict__ a2raw, float* __restrict__ biastab,
    ushort_t* __restrict__ wb, float* __restrict__ statsbuf)
{
  const int chunk = blockIdx.x;                 // 0..128
  const int n = blockIdx.y;
  const int tid = threadIdx.x;

  if (chunk == 128) {                           // ---- prep block ----
    if (n != 0) return;
    __shared__ float colA[P_ * 32];
    if (tid < P_ * 32) {
      int p = tid >> 5, w = tid & 31;
      float s = 0.f;
      if (w < V_)
        for (int v = 0; v < V_; ++v) {
          int idx = (p * V_ + v) * V_ + w;
          s += A[idx] * E[idx];
        }
      colA[tid] = s;
    }
    for (int e = tid; e < 32 * 96; e += 256) {
      int w = e / 96, k = e - w * 96;
      int p = k >> 5, v = k & 31;
      float val = 0.f;
      if (w < V_ && v < V_) {
        int idx = (p * V_ + v) * V_ + w;
        val = A[idx] * E[idx];
      }
      a2raw[e] = f2b(val);
    }
    for (int e = tid; e < 192 * 64; e += 256) wb[e] = f2b(W[e]);
    __syncthreads();
    for (int e = tid; e < 32 * 64; e += 256) {
      int w = e >> 6, c = e & 63;
      float s = 0.f;
      for (int p = 0; p < P_; ++p) s += cb[p * 64 + c] * colA[p * 32 + w];
      biastab[e] = s;
    }
    for (int e = tid; e < NREP * 128; e += 256) statsbuf[e] = 0.f;
    return;
  }

  // ---- window block ----
  __shared__ ushort_t tile[64 * 402];           // 51.5 KB; stride 402 (odd dword)
  const int l0 = chunk * 8;
  const long xn = (long)n * CI_ * L_ * V_;
  for (int m = tid; m < 6400; m += 256) {       // 64 ci x 400 f32 -> bf16
    int ci = m / 100;
    int j4 = (m - ci * 100) * 4;                // 0..396
    f32x4 d;
    if (chunk == 0 && j4 < 200) {
      d = (f32x4){0.f, 0.f, 0.f, 0.f};          // l < 0 halo (li 0..7)
    } else {
      d = *(const f32x4*)(x + xn + (long)ci * (L_ * V_) + (l0 - 8) * V_ + j4);
    }
    ushort_t* dst = &tile[ci * 402 + j4];
    dst[0] = f2b(d[0]); dst[1] = f2b(d[1]); dst[2] = f2b(d[2]); dst[3] = f2b(d[3]);
  }
  __syncthreads();
  // sliding window per (v,ci) column; coalesced b16 stores per l_.
  const long xsbase = ((long)n * L_ + l0) * 1600;
  for (int cid = tid; cid < 1600; cid += 256) {
    const int v = cid >> 6, ci = cid & 63;
    const ushort_t* col = &tile[ci * 402 + v];  // + li*25 steps along l
    float s = 0.f;
#pragma unroll
    for (int li = 0; li < 9; ++li) s += b2f(col[li * 25]);
    xs[xsbase + cid] = f2b(s);                  // l_ = 0 (li window 0..8)
#pragma unroll
    for (int l_ = 1; l_ < 8; ++l_) {
      s += b2f(col[(l_ + 8) * 25]) - b2f(col[(l_ - 1) * 25]);
      xs[xsbase + l_ * 1600 + cid] = f2b(s);
    }
  }
}

// ---------------------------------------------------------------------------
// kmain: per-(n, 4 l's) block; single 26.6 KB T1, 3 barriers, ~4 blocks/CU.
//   per pair (l01 then l23):
//     stage1: t1 = Wb[192x64] @ Xs[64 x 64cols]; B-frags direct from global xs
//     stage2: z[c=64][w=32] per l = T1c[64x96] @ A2[96x32]; + cnt(l)*bias
//     epilogue: us4 zb stores; BN-stats accumulate in registers
//   tail: in-quad shuffle reduce + replicated statsbuf atomics.
__global__ __launch_bounds__(256, 4) void kmain(
    const ushort_t* __restrict__ xs,      // [n][l][1600] bf16 (L2-hot)
    const ushort_t* __restrict__ Wb,      // [192][64] bf16 (L1-hot)
    const ushort_t* __restrict__ a2,      // [32 w][96 k] bf16 (L1-hot)
    const float*    __restrict__ biastab, // [32 w][64 c] f32 (L1-hot)
    ushort_t*       __restrict__ zb,
    float*          __restrict__ statsbuf)
{
  const int lb = blockIdx.x;            // 4 l's per block (0..255)
  const int n  = blockIdx.y;
  const int tid = threadIdx.x, lane = tid & 63, wv = tid >> 6;
  const int m16 = lane & 15, quad = lane >> 4;

  __shared__ __align__(16) ushort_t T1[13312];   // [l_][c][104]  26.6 KB

  // hoist Wb A-frags once (reused by both pairs)
  short8 af[3][2];
#pragma unroll
  for (int i = 0; i < 3; ++i) {
    const ushort_t* wrow = Wb + ((wv * 3 + i) * 16 + m16) * 64 + quad * 8;
    af[i][0] = *(const short8*)(wrow);
    af[i][1] = *(const short8*)(wrow + 32);
  }

  const ushort_t* xsb = xs + ((long)n * L_ + 4 * lb) * 1600;
  const int cbase = wv * 16 + quad * 4;
  float s1[4] = {0.f, 0.f, 0.f, 0.f}, s2[4] = {0.f, 0.f, 0.f, 0.f};

#pragma unroll
  for (int pair = 0; pair < 2; ++pair) {
    // ---- stage 1: B-frags direct from global xs (predicated zero v>=25) ----
    short8 bfr[4][2];
#pragma unroll
    for (int nt = 0; nt < 4; ++nt) {
      const int v = (nt & 1) * 16 + m16;
      const int l_ = pair * 2 + (nt >> 1);
#pragma unroll
      for (int ks = 0; ks < 2; ++ks) {
        short8 t = (short8){0, 0, 0, 0, 0, 0, 0, 0};
        if (v < V_)
          t = *(const short8*)(xsb + l_ * 1600 + v * 64 + ks * 32 + quad * 8);
        bfr[nt][ks] = t;
      }
    }

    f32x4 acc1[3][4];
#pragma unroll
    for (int i = 0; i < 3; ++i)
#pragma unroll
      for (int j = 0; j < 4; ++j) acc1[i][j] = (f32x4){0.f, 0.f, 0.f, 0.f};

#pragma unroll
    for (int i = 0; i < 3; ++i)
#pragma unroll
      for (int nt = 0; nt < 4; ++nt) {
        acc1[i][nt] = __builtin_amdgcn_mfma_f32_16x16x32_bf16(af[i][0], bfr[nt][0], acc1[i][nt], 0, 0, 0);
        acc1[i][nt] = __builtin_amdgcn_mfma_f32_16x16x32_bf16(af[i][1], bfr[nt][1], acc1[i][nt], 0, 0, 0);
      }

    if (pair) __syncthreads();          // prior pair's T1 reads complete
    // repack t1 -> T1[l_][c][p*32+v]  (D: row = quad*4+r, col = m16)
#pragma unroll
    for (int i = 0; i < 3; ++i) {
      const int mt = wv * 3 + i;
#pragma unroll
      for (int nt = 0; nt < 4; ++nt) {
        const int l_ = nt >> 1;
        const int col = (nt & 1) * 16 + m16;
#pragma unroll
        for (int r = 0; r < 4; ++r) {
          int k = mt * 16 + quad * 4 + r;        // k = p*64 + c
          T1[l_ * 6656 + (k & 63) * 104 + (k >> 6) * 32 + col] = f2b(acc1[i][nt][r]);
        }
      }
    }
    __syncthreads();

    // ---- stage 2: 12 MFMA; a2 B-frags loaded per pair (global, L1-hot) ----
    short8 bfr2[2][3];
#pragma unroll
    for (int nt = 0; nt < 2; ++nt)
#pragma unroll
      for (int ks = 0; ks < 3; ++ks)
        bfr2[nt][ks] = *(const short8*)(a2 + (nt * 16 + m16) * 96 + ks * 32 + quad * 8);

    f32x4 acc2[2][2];
#pragma unroll
    for (int l_ = 0; l_ < 2; ++l_)
#pragma unroll
      for (int nt = 0; nt < 2; ++nt) acc2[l_][nt] = (f32x4){0.f, 0.f, 0.f, 0.f};

#pragma unroll
    for (int l_ = 0; l_ < 2; ++l_)
#pragma unroll
      for (int ks = 0; ks < 3; ++ks) {
        short8 afT = *(const short8*)(&T1[l_ * 6656 + (wv * 16 + m16) * 104 + ks * 32 + quad * 8]);
        acc2[l_][0] = __builtin_amdgcn_mfma_f32_16x16x32_bf16(afT, bfr2[0][ks], acc2[l_][0], 0, 0, 0);
        acc2[l_][1] = __builtin_amdgcn_mfma_f32_16x16x32_bf16(afT, bfr2[1][ks], acc2[l_][1], 0, 0, 0);
      }

    // epilogue: + cnt(l)*bias (float4), us4 store; accumulate BN stats
#pragma unroll
    for (int l_ = 0; l_ < 2; ++l_) {
      const int l = 4 * lb + pair * 2 + l_;
      const float cnt = (float)(l + 1 < KS_ ? l + 1 : KS_);
#pragma unroll
      for (int nt = 0; nt < 2; ++nt) {
        const int w = nt * 16 + m16;
        if (w < V_) {
          f32x4 bias = *(const f32x4*)(biastab + w * 64 + cbase);
          us4 pack;
#pragma unroll
          for (int r = 0; r < 4; ++r) {
            pack[r] = f2b(acc2[l_][nt][r] + cnt * bias[r]);
            float zr = b2f(pack[r]);            // stats on the stored value
            s1[r] += zr; s2[r] += zr * zr;
          }
          *(us4*)(&zb[(((long)(n * L_ + l) * V_ + w) << 6) + cbase]) = pack;
        }
      }
    }
  }
  // in-quad reduction over m16 (lanes of a quad share channels cbase..cbase+3)
#pragma unroll
  for (int off = 1; off < 16; off <<= 1) {
#pragma unroll
    for (int r = 0; r < 4; ++r) {
      s1[r] += __shfl_xor(s1[r], off, 64);
      s2[r] += __shfl_xor(s2[r], off, 64);
    }
  }
  if (m16 == 0) {
    float* sb = statsbuf + ((n * 256 + lb) & (NREP - 1)) * 128;
#pragma unroll
    for (int r = 0; r < 4; ++r) {
      atomicAdd(&sb[cbase + r], s1[r]);
      atomicAdd(&sb[64 + cbase + r], s2[r]);
    }
  }
}

// ---------------------------------------------------------------------------
// kapply: reduce statsbuf copies (L2-hot) -> mean/var, then
// out[n,c,l,v] = relu(relu((z-mean)*rstd*g+b) + x).  8 l's per block, f32x4.
__global__ __launch_bounds__(256) void kapply(
    const ushort_t* __restrict__ zb, const float* __restrict__ x,
    const float* __restrict__ statsbuf,
    const float* __restrict__ gamma, const float* __restrict__ beta,
    float* __restrict__ out)
{
  const int n = blockIdx.y, chunk = blockIdx.x;   // 8 l's per block
  const int tid = threadIdx.x;
  __shared__ ushort_t zl[200 * 66];               // 26.4 KB transpose staging
  __shared__ float red[4][64][2];
  __shared__ float sc[64], sh[64];
  const long zbase = (long)((n * L_ + chunk * 8) * V_) * 64;   // 12800 elems
  for (int m = tid; m < 6400; m += 256) {         // u32 = 2 bf16
    *(unsigned int*)(&zl[(m >> 5) * 66 + (m & 31) * 2]) =
        ((const unsigned int*)(zb + zbase))[m];
  }
  // reduce the NREP stats copies (64-KB L2-hot region)
  {
    const int c = tid & 63, grp = tid >> 6;       // 4 groups x 64 channels
    float a = 0.f, b = 0.f;
    for (int k = grp; k < NREP; k += 4) {
      a += statsbuf[k * 128 + c];
      b += statsbuf[k * 128 + 64 + c];
    }
    red[grp][c][0] = a;
    red[grp][c][1] = b;
  }
  __syncthreads();
  if (tid < 64) {
    const float inv = 1.0f / NLV;
    float s  = red[0][tid][0] + red[1][tid][0] + red[2][tid][0] + red[3][tid][0];
    float sq = red[0][tid][1] + red[1][tid][1] + red[2][tid][1] + red[3][tid][1];
    float mean = s * inv;
    float var  = sq * inv - mean * mean;
    float rstd = rsqrtf(var + 1e-5f);
    float g = gamma[tid];
    sc[tid] = rstd * g;
    sh[tid] = beta[tid] - mean * rstd * g;
  }
  __syncthreads();
  const long obase = ((long)(n * 64) * L_ + chunk * 8) * V_;   // + c*25600 + rr
  for (int m = tid; m < 3200; m += 256) {
    int c = m / 50, q = m - c * 50, rr = q * 4;   // rr = 4-aligned l*25+v
    long xi = obase + (long)c * (L_ * V_) + rr;
    f32x4 xv = *(const f32x4*)(x + xi);
    f32x4 o;
#pragma unroll
    for (int j = 0; j < 4; ++j) {
      float z = b2f(zl[(rr + j) * 66 + c]);
      float y = fmaxf(z * sc[c] + sh[c], 0.f);
      o[j] = fmaxf(y + xv[j], 0.f);
    }
    *(f32x4*)(out + xi) = o;
  }
}

// ---------------------------------------------------------------------------
extern "C" void kernel_launch(void* const* d_in, const int* in_sizes, int n_in,
                              void* d_out, int out_size, void* d_ws, size_t ws_size,
                              hipStream_t stream)
{
  const float* x     = (const float*)d_in[0];
  const float* A     = (const float*)d_in[1];
  const float* E     = (const float*)d_in[2];
  const float* W     = (const float*)d_in[3];
  const float* cb    = (const float*)d_in[4];
  const float* gamma = (const float*)d_in[5];
  const float* beta  = (const float*)d_in[6];
  float* out = (float*)d_out;

  char* ws = (char*)d_ws;
  const size_t XS_OFF   = 0;                       // 13,107,200 B (bf16 xs)
  const size_t ZB_OFF   = 13107200;                // 13,107,200 B (bf16 zb)
  const size_t WB_OFF   = 26214400;                // 24,576 B (bf16 Wb)
  const size_t A2_OFF   = WB_OFF + 32768;          // 6,144 B
  const size_t BIAS_OFF = A2_OFF + 16384;          // 8,192 B
  const size_t STAT_OFF = BIAS_OFF + 16384;        // 65,536 B (128 x 128 f32)
  ushort_t* xs       = (ushort_t*)(ws + XS_OFF);
  ushort_t* zb       = (ushort_t*)(ws + ZB_OFF);
  ushort_t* wb       = (ushort_t*)(ws + WB_OFF);
  ushort_t* a2       = (ushort_t*)(ws + A2_OFF);
  float*    biastab  = (float*)(ws + BIAS_OFF);
  float*    statsbuf = (float*)(ws + STAT_OFF);

  kwin  <<<dim3(129, N_), 256, 0, stream>>>(x, xs, A, E, cb, W, a2, biastab, wb,
                                            statsbuf);
  kmain <<<dim3(256, N_), 256, 0, stream>>>(xs, wb, a2, biastab, zb, statsbuf);
  kapply<<<dim3(128, N_), 256, 0, stream>>>(zb, x, statsbuf, gamma, beta, out);
}